// Round 2
// baseline (539.758 us; speedup 1.0000x reference)
//
#include <hip/hip_runtime.h>
#include <cstdint>
#include <cstddef>

using u16 = unsigned short;
typedef __attribute__((ext_vector_type(8))) short bh8;   // 8 x bf16 (4 VGPRs)
typedef __attribute__((ext_vector_type(4))) float f4;    // MFMA accumulator

// ---------- helpers ----------
__device__ __forceinline__ u16 f2bf(float f) {
    union { float f; uint32_t u; } c; c.f = f;
    uint32_t u = c.u;
    u += 0x7FFFu + ((u >> 16) & 1u);   // RNE
    return (u16)(u >> 16);
}

__device__ __forceinline__ void gload16(const void* g, void* l) {
    // async global->LDS, 16B per lane; LDS dest = wave-uniform base + lane*16
    __builtin_amdgcn_global_load_lds(
        (__attribute__((address_space(1))) void*)g,
        (__attribute__((address_space(3))) void*)l,
        16, 0, 0);
}

__device__ __forceinline__ f4 mfma16(bh8 a, bh8 b, f4 c) {
    return __builtin_amdgcn_mfma_f32_16x16x32_bf16(a, b, c, 0, 0, 0);
}

// ---------- weight transpose + f32 -> bf16 ----------
// W [K][N] f32  ->  Wt [N][K] bf16
__global__ __launch_bounds__(256) void wconv_kernel(
    const float* __restrict__ W, u16* __restrict__ Wt, int K, int N)
{
    __shared__ float t[32][33];
    const int tx = threadIdx.x & 31, ty = threadIdx.x >> 5;
    const int n0 = blockIdx.x * 32, k0 = blockIdx.y * 32;
#pragma unroll
    for (int j = 0; j < 4; ++j)
        t[ty + 8 * j][tx] = W[(size_t)(k0 + ty + 8 * j) * N + n0 + tx];
    __syncthreads();
#pragma unroll
    for (int j = 0; j < 4; ++j)
        Wt[(size_t)(n0 + ty + 8 * j) * K + k0 + tx] = f2bf(t[tx][ty + 8 * j]);
}

// ---------- layernorm: f32 [rows][1024] -> bf16 ----------
__global__ __launch_bounds__(256) void ln_kernel(
    const float* __restrict__ x, const float* __restrict__ g,
    const float* __restrict__ b, u16* __restrict__ out)
{
    const int row = blockIdx.x;
    const int tid = threadIdx.x;
    const float4 v = ((const float4*)(x + (size_t)row * 1024))[tid];
    float s  = v.x + v.y + v.z + v.w;
    float sq = v.x * v.x + v.y * v.y + v.z * v.z + v.w * v.w;
#pragma unroll
    for (int m = 1; m < 64; m <<= 1) {
        s  += __shfl_xor(s, m);
        sq += __shfl_xor(sq, m);
    }
    __shared__ float red[8];
    const int w = tid >> 6;
    if ((tid & 63) == 0) { red[w * 2] = s; red[w * 2 + 1] = sq; }
    __syncthreads();
    s  = red[0] + red[2] + red[4] + red[6];
    sq = red[1] + red[3] + red[5] + red[7];
    const float mu   = s * (1.0f / 1024.0f);
    const float var  = sq * (1.0f / 1024.0f) - mu * mu;
    const float rstd = rsqrtf(var + 1e-5f);
    const float4 gv = ((const float4*)g)[tid];
    const float4 bv = ((const float4*)b)[tid];
    ushort4 o;
    o.x = f2bf((v.x - mu) * rstd * gv.x + bv.x);
    o.y = f2bf((v.y - mu) * rstd * gv.y + bv.y);
    o.z = f2bf((v.z - mu) * rstd * gv.z + bv.z);
    o.w = f2bf((v.w - mu) * rstd * gv.w + bv.w);
    ((ushort4*)(out + (size_t)row * 1024))[tid] = o;
}

// ---------- bf16 GEMM:  C[M][N] = A[M][K] * Bt[N][K]^T  (+ epilogue) ----------
// EPI 0: outb = bf16(acc)                      (QKV)
// EPI 1: outf = resid + acc + bias             (proj residual / FFN2 residual)
// EPI 2: outb = bf16(relu(acc + bias))         (FFN1)
template <int EPI>
__global__ __launch_bounds__(256, 2) void gemm_kernel(
    const u16* __restrict__ A, const u16* __restrict__ Bt,
    int M, int N, int K,
    const float* __restrict__ bias, const float* __restrict__ resid,
    float* __restrict__ outf, u16* __restrict__ outb)
{
    __shared__ u16 Al[128 * 64];
    __shared__ u16 Bl[128 * 64];
    const int tid  = threadIdx.x;
    const int lane = tid & 63;
    const int w    = tid >> 6;
    const int wr   = w >> 1, wc = w & 1;
    const int mt   = blockIdx.y, nt = blockIdx.x;
    const int lrow = lane & 15;
    const int lkb  = (lane >> 4) * 8;
    const int rs   = tid >> 3;       // staging: row-within-32-row group
    const int cs   = tid & 7;        // staging: 16B chunk within row (8 chunks = 64 cols)

    f4 acc[4][4] = {};

    for (int k0 = 0; k0 < K; k0 += 64) {
#pragma unroll
        for (int it = 0; it < 4; ++it) {
            const int r = it * 32 + rs;
            gload16(A + (size_t)(mt * 128 + r) * K + k0 + cs * 8,
                    (char*)Al + (it * 256 + w * 64) * 16);
        }
#pragma unroll
        for (int it = 0; it < 4; ++it) {
            const int r = it * 32 + rs;
            gload16(Bt + (size_t)(nt * 128 + r) * K + k0 + cs * 8,
                    (char*)Bl + (it * 256 + w * 64) * 16);
        }
        __syncthreads();
#pragma unroll
        for (int ks = 0; ks < 2; ++ks) {
            bh8 af[4], bv[4];
#pragma unroll
            for (int fm = 0; fm < 4; ++fm)
                af[fm] = *(const bh8*)&Al[(wr * 64 + fm * 16 + lrow) * 64 + ks * 32 + lkb];
#pragma unroll
            for (int fn = 0; fn < 4; ++fn)
                bv[fn] = *(const bh8*)&Bl[(wc * 64 + fn * 16 + lrow) * 64 + ks * 32 + lkb];
#pragma unroll
            for (int fm = 0; fm < 4; ++fm)
#pragma unroll
                for (int fn = 0; fn < 4; ++fn)
                    acc[fm][fn] = mfma16(af[fm], bv[fn], acc[fm][fn]);
        }
        __syncthreads();
    }

    const int r0 = mt * 128 + wr * 64 + (lane >> 4) * 4;
    const int c0 = nt * 128 + wc * 64 + lrow;
#pragma unroll
    for (int fn = 0; fn < 4; ++fn) {
        const int col = c0 + fn * 16;
        const float bvl = (EPI != 0) ? bias[col] : 0.0f;
#pragma unroll
        for (int fm = 0; fm < 4; ++fm) {
#pragma unroll
            for (int i = 0; i < 4; ++i) {
                const size_t idx = (size_t)(r0 + fm * 16 + i) * N + col;
                const float v = acc[fm][fn][i];
                if (EPI == 0)      outb[idx] = f2bf(v);
                else if (EPI == 1) outf[idx] = resid[idx] + v + bvl;
                else               outb[idx] = f2bf(fmaxf(v + bvl, 0.0f));
            }
        }
    }
}

// ---------- causal flash attention, bf16 MFMA ----------
// Q,K,V,O: bf16 [b*1024 + t][h*64 + d] (row stride 1024). grid = (16 qtiles, 128 bh)
__global__ __launch_bounds__(256, 2) void attn_kernel(
    const u16* __restrict__ Q, const u16* __restrict__ K,
    const u16* __restrict__ V, u16* __restrict__ O)
{
    __shared__ u16 Ql[64 * 64];
    __shared__ u16 Kl[64 * 64];
    __shared__ u16 Vt[64 * 64];          // transposed: Vt[d][s]
    __shared__ u16 Pl[4][16 * 64];       // per-wave P strip

    const int tid  = threadIdx.x;
    const int lane = tid & 63;
    const int w    = tid >> 6;
    const int qt   = blockIdx.x;
    const int bh   = blockIdx.y;
    const int b    = bh >> 4, h = bh & 15;
    const size_t base = (size_t)b * 1024 * 1024 + h * 64;
    const int q0   = qt * 64;
    const int lrow = lane & 15;
    const int lkb  = (lane >> 4) * 8;
    const int rs   = tid >> 3, cs = tid & 7;

    // stage Q tile (64 rows x 64 d)
#pragma unroll
    for (int it = 0; it < 2; ++it) {
        const int r = it * 32 + rs;
        gload16(Q + base + (size_t)(q0 + r) * 1024 + cs * 8,
                (char*)Ql + (it * 256 + w * 64) * 16);
    }

    f4 o[4] = {};
    float mi[4], li[4];
#pragma unroll
    for (int i = 0; i < 4; ++i) { mi[i] = -__builtin_inff(); li[i] = 0.0f; }

    for (int s0 = 0; s0 <= q0; s0 += 64) {
        // stage K tile
#pragma unroll
        for (int it = 0; it < 2; ++it) {
            const int r = it * 32 + rs;
            gload16(K + base + (size_t)(s0 + r) * 1024 + cs * 8,
                    (char*)Kl + (it * 256 + w * 64) * 16);
        }
        // stage V transposed (reg staging + scalar LDS writes)
#pragma unroll
        for (int it = 0; it < 2; ++it) {
            const int s = it * 32 + rs;
            const uint4 dv = *(const uint4*)(V + base + (size_t)(s0 + s) * 1024 + cs * 8);
            const uint32_t arr[4] = { dv.x, dv.y, dv.z, dv.w };
#pragma unroll
            for (int e = 0; e < 4; ++e) {
                Vt[(cs * 8 + 2 * e + 0) * 64 + s] = (u16)(arr[e] & 0xFFFFu);
                Vt[(cs * 8 + 2 * e + 1) * 64 + s] = (u16)(arr[e] >> 16);
            }
        }
        __syncthreads();

        // scores = Q K^T : wave w owns q rows [q0 + w*16, +16)
        f4 sc[4] = {};
#pragma unroll
        for (int ks = 0; ks < 2; ++ks) {
            const bh8 aq = *(const bh8*)&Ql[(w * 16 + lrow) * 64 + ks * 32 + lkb];
#pragma unroll
            for (int fn = 0; fn < 4; ++fn) {
                const bh8 bk = *(const bh8*)&Kl[(fn * 16 + lrow) * 64 + ks * 32 + lkb];
                sc[fn] = mfma16(aq, bk, sc[fn]);
            }
        }
        // scale + causal mask (diagonal tile only)
        // wave w owns q-local rows w*16 + r (r = (lane>>4)*4 + i); key col c.
        // allowed: c <= w*16 + r
        const bool diag = (s0 == q0);
#pragma unroll
        for (int fn = 0; fn < 4; ++fn)
#pragma unroll
            for (int i = 0; i < 4; ++i) {
                float v = sc[fn][i] * 0.125f;
                if (diag) {
                    const int r = (lane >> 4) * 4 + i;
                    const int c = fn * 16 + lrow;
                    if (c > w * 16 + r) v = -__builtin_inff();
                }
                sc[fn][i] = v;
            }
        // online softmax, per q-row (row = 4*(lane>>4)+i, replicated across 16 lanes)
#pragma unroll
        for (int i = 0; i < 4; ++i) {
            float pm = fmaxf(fmaxf(sc[0][i], sc[1][i]), fmaxf(sc[2][i], sc[3][i]));
#pragma unroll
            for (int m = 1; m < 16; m <<= 1) pm = fmaxf(pm, __shfl_xor(pm, m));
            const float mn   = fmaxf(mi[i], pm);
            const float corr = __expf(mi[i] - mn);
            float rsum = 0.0f;
#pragma unroll
            for (int fn = 0; fn < 4; ++fn) {
                const float p = __expf(sc[fn][i] - mn);
                sc[fn][i] = p;
                rsum += p;
            }
#pragma unroll
            for (int m = 1; m < 16; m <<= 1) rsum += __shfl_xor(rsum, m);
            li[i] = li[i] * corr + rsum;
            mi[i] = mn;
#pragma unroll
            for (int fn = 0; fn < 4; ++fn) o[fn][i] *= corr;
        }
        // write P strip (bf16), wave-private
#pragma unroll
        for (int fn = 0; fn < 4; ++fn)
#pragma unroll
            for (int i = 0; i < 4; ++i)
                Pl[w][((lane >> 4) * 4 + i) * 64 + fn * 16 + lrow] = f2bf(sc[fn][i]);
        // PV: O += P * V
#pragma unroll
        for (int ss = 0; ss < 2; ++ss) {
            const bh8 ap = *(const bh8*)&Pl[w][lrow * 64 + ss * 32 + lkb];
#pragma unroll
            for (int fn = 0; fn < 4; ++fn) {
                const bh8 bv = *(const bh8*)&Vt[(fn * 16 + lrow) * 64 + ss * 32 + lkb];
                o[fn] = mfma16(ap, bv, o[fn]);
            }
        }
        __syncthreads();
    }

    // write O (bf16)
#pragma unroll
    for (int fn = 0; fn < 4; ++fn)
#pragma unroll
        for (int i = 0; i < 4; ++i) {
            const int r = q0 + w * 16 + (lane >> 4) * 4 + i;
            const int c = fn * 16 + lrow;
            O[base + (size_t)r * 1024 + c] = f2bf(o[fn][i] / li[i]);
        }
}

// ---------- launch ----------
extern "C" void kernel_launch(void* const* d_in, const int* in_sizes, int n_in,
                              void* d_out, int out_size, void* d_ws, size_t ws_size,
                              hipStream_t stream) {
    const float* x    = (const float*)d_in[0];
    const float* Wq   = (const float*)d_in[1];
    const float* Wk   = (const float*)d_in[2];
    const float* Wv   = (const float*)d_in[3];
    const float* Wp   = (const float*)d_in[4];
    const float* bp   = (const float*)d_in[5];
    const float* ln1g = (const float*)d_in[6];
    const float* ln1b = (const float*)d_in[7];
    const float* ln2g = (const float*)d_in[8];
    const float* ln2b = (const float*)d_in[9];
    const float* W1   = (const float*)d_in[10];
    const float* b1   = (const float*)d_in[11];
    const float* W2   = (const float*)d_in[12];
    const float* b2   = (const float*)d_in[13];
    float* out = (float*)d_out;

    // ws layout (u16 elements). Peak usage: 104 MB.
    u16* ws   = (u16*)d_ws;
    u16* wqt  = ws;                       // [1024][1024]
    u16* wkt  = wqt + (1u << 20);
    u16* wvt  = wkt + (1u << 20);
    u16* wpt  = wvt + (1u << 20);
    u16* w1t  = wpt + (1u << 20);         // [4096][1024]
    u16* w2t  = w1t + (4u << 20);         // [1024][4096]
    u16* qb   = w2t + (4u << 20);         // [8192][1024]
    u16* kb   = qb  + (8u << 20);
    u16* vb   = kb  + (8u << 20);
    u16* xnb  = vb  + (8u << 20);         // xn; reused as attn-out
    u16* aob  = xnb;
    u16* xn2b = qb;                       // q dead after attention
    u16* h1b  = kb;                       // [8192][4096] overlays k,v,xn + 16MB

    dim3 blk(256);
    wconv_kernel<<<dim3(32, 32),  blk, 0, stream>>>(Wq, wqt, 1024, 1024);
    wconv_kernel<<<dim3(32, 32),  blk, 0, stream>>>(Wk, wkt, 1024, 1024);
    wconv_kernel<<<dim3(32, 32),  blk, 0, stream>>>(Wv, wvt, 1024, 1024);
    wconv_kernel<<<dim3(32, 32),  blk, 0, stream>>>(Wp, wpt, 1024, 1024);
    wconv_kernel<<<dim3(128, 32), blk, 0, stream>>>(W1, w1t, 1024, 4096);
    wconv_kernel<<<dim3(32, 128), blk, 0, stream>>>(W2, w2t, 4096, 1024);

    ln_kernel<<<8192, blk, 0, stream>>>(x, ln1g, ln1b, xnb);

    gemm_kernel<0><<<dim3(8, 64), blk, 0, stream>>>(xnb, wqt, 8192, 1024, 1024,
                                                    nullptr, nullptr, nullptr, qb);
    gemm_kernel<0><<<dim3(8, 64), blk, 0, stream>>>(xnb, wkt, 8192, 1024, 1024,
                                                    nullptr, nullptr, nullptr, kb);
    gemm_kernel<0><<<dim3(8, 64), blk, 0, stream>>>(xnb, wvt, 8192, 1024, 1024,
                                                    nullptr, nullptr, nullptr, vb);

    attn_kernel<<<dim3(16, 128), blk, 0, stream>>>(qb, kb, vb, aob);

    gemm_kernel<1><<<dim3(8, 64), blk, 0, stream>>>(aob, wpt, 8192, 1024, 1024,
                                                    bp, x, out, nullptr);

    ln_kernel<<<8192, blk, 0, stream>>>(out, ln2g, ln2b, xn2b);

    gemm_kernel<2><<<dim3(32, 64), blk, 0, stream>>>(xn2b, w1t, 8192, 4096, 1024,
                                                     b1, nullptr, nullptr, h1b);
    gemm_kernel<1><<<dim3(8, 64), blk, 0, stream>>>(h1b, w2t, 8192, 1024, 4096,
                                                    b2, out, out, nullptr);
}

// Round 3
// 398.921 us; speedup vs baseline: 1.3530x; 1.3530x over previous
//
#include <hip/hip_runtime.h>
#include <cstdint>
#include <cstddef>

using u16 = unsigned short;
typedef __attribute__((ext_vector_type(8))) short bh8;   // 8 x bf16 (4 VGPRs)
typedef __attribute__((ext_vector_type(4))) float f4;    // MFMA accumulator

// ---------- helpers ----------
__device__ __forceinline__ u16 f2bf(float f) {
    union { float f; uint32_t u; } c; c.f = f;
    uint32_t u = c.u;
    u += 0x7FFFu + ((u >> 16) & 1u);   // RNE
    return (u16)(u >> 16);
}

__device__ __forceinline__ void gload16(const void* g, void* l) {
    // async global->LDS, 16B per lane; LDS dest = wave-uniform base + lane*16
    __builtin_amdgcn_global_load_lds(
        (__attribute__((address_space(1))) void*)g,
        (__attribute__((address_space(3))) void*)l,
        16, 0, 0);
}

__device__ __forceinline__ f4 mfma16(bh8 a, bh8 b, f4 c) {
    return __builtin_amdgcn_mfma_f32_16x16x32_bf16(a, b, c, 0, 0, 0);
}

// ---------- weight transpose + f32 -> bf16 ----------
// W [K][N] f32  ->  Wt [N][K] bf16
__global__ __launch_bounds__(256) void wconv_kernel(
    const float* __restrict__ W, u16* __restrict__ Wt, int K, int N)
{
    __shared__ float t[32][33];
    const int tx = threadIdx.x & 31, ty = threadIdx.x >> 5;
    const int n0 = blockIdx.x * 32, k0 = blockIdx.y * 32;
#pragma unroll
    for (int j = 0; j < 4; ++j)
        t[ty + 8 * j][tx] = W[(size_t)(k0 + ty + 8 * j) * N + n0 + tx];
    __syncthreads();
#pragma unroll
    for (int j = 0; j < 4; ++j)
        Wt[(size_t)(n0 + ty + 8 * j) * K + k0 + tx] = f2bf(t[tx][ty + 8 * j]);
}

// ---------- layernorm: f32 [rows][1024] -> bf16 ----------
__global__ __launch_bounds__(256) void ln_kernel(
    const float* __restrict__ x, const float* __restrict__ g,
    const float* __restrict__ b, u16* __restrict__ out)
{
    const int row = blockIdx.x;
    const int tid = threadIdx.x;
    const float4 v = ((const float4*)(x + (size_t)row * 1024))[tid];
    float s  = v.x + v.y + v.z + v.w;
    float sq = v.x * v.x + v.y * v.y + v.z * v.z + v.w * v.w;
#pragma unroll
    for (int m = 1; m < 64; m <<= 1) {
        s  += __shfl_xor(s, m);
        sq += __shfl_xor(sq, m);
    }
    __shared__ float red[8];
    const int w = tid >> 6;
    if ((tid & 63) == 0) { red[w * 2] = s; red[w * 2 + 1] = sq; }
    __syncthreads();
    s  = red[0] + red[2] + red[4] + red[6];
    sq = red[1] + red[3] + red[5] + red[7];
    const float mu   = s * (1.0f / 1024.0f);
    const float var  = sq * (1.0f / 1024.0f) - mu * mu;
    const float rstd = rsqrtf(var + 1e-5f);
    const float4 gv = ((const float4*)g)[tid];
    const float4 bv = ((const float4*)b)[tid];
    ushort4 o;
    o.x = f2bf((v.x - mu) * rstd * gv.x + bv.x);
    o.y = f2bf((v.y - mu) * rstd * gv.y + bv.y);
    o.z = f2bf((v.z - mu) * rstd * gv.z + bv.z);
    o.w = f2bf((v.w - mu) * rstd * gv.w + bv.w);
    ((ushort4*)(out + (size_t)row * 1024))[tid] = o;
}

// ---------- V transpose: vb [8192][1024] -> vtb [bh][64 d][1024 t] ----------
__global__ __launch_bounds__(256) void vtrans_kernel(
    const u16* __restrict__ vb, u16* __restrict__ vtb)
{
    __shared__ u16 t[64][66];
    const int bh = blockIdx.y;
    const int t0 = blockIdx.x * 64;
    const int b = bh >> 4, h = bh & 15;
    const u16* src = vb + (size_t)b * 1024 * 1024 + h * 64;
    const int rs = threadIdx.x >> 3, cs = threadIdx.x & 7;
#pragma unroll
    for (int it = 0; it < 2; ++it) {
        const int r = it * 32 + rs;
        *(uint4*)&t[r][cs * 8] = *(const uint4*)(src + (size_t)(t0 + r) * 1024 + cs * 8);
    }
    __syncthreads();
    u16* dst = vtb + (size_t)bh * 65536 + t0;
#pragma unroll
    for (int it = 0; it < 2; ++it) {
        const int d = it * 32 + rs;
        u16 tmp[8];
#pragma unroll
        for (int j = 0; j < 8; ++j) tmp[j] = t[cs * 8 + j][d];
        *(uint4*)(dst + (size_t)d * 1024 + cs * 8) = *(const uint4*)tmp;
    }
}

// ---------- bf16 GEMM:  C[M][N] = A[M][K] * Bt[N][K]^T  (+ epilogue) ----------
// EPI 0: outb = bf16(acc)
// EPI 1: outf = resid + acc + bias             (proj residual / FFN2 residual)
// EPI 2: outb = bf16(relu(acc + bias))         (FFN1)
// EPI 3: qkv split: col>>10 selects q/k/v segment (each 8M u16, contiguous)
template <int EPI>
__global__ __launch_bounds__(256, 2) void gemm_kernel(
    const u16* __restrict__ A, const u16* __restrict__ Bt,
    int M, int N, int K,
    const float* __restrict__ bias, const float* __restrict__ resid,
    float* __restrict__ outf, u16* __restrict__ outb)
{
    __shared__ u16 Al[128 * 64];
    __shared__ u16 Bl[128 * 64];
    const int tid  = threadIdx.x;
    const int lane = tid & 63;
    const int w    = tid >> 6;
    const int wr   = w >> 1, wc = w & 1;
    const int mt   = blockIdx.y, nt = blockIdx.x;
    const int lrow = lane & 15;
    const int lkb  = (lane >> 4) * 8;
    const int rs   = tid >> 3;
    const int cs   = tid & 7;

    f4 acc[4][4] = {};

    for (int k0 = 0; k0 < K; k0 += 64) {
#pragma unroll
        for (int it = 0; it < 4; ++it) {
            const int r = it * 32 + rs;
            gload16(A + (size_t)(mt * 128 + r) * K + k0 + cs * 8,
                    (char*)Al + (it * 256 + w * 64) * 16);
        }
#pragma unroll
        for (int it = 0; it < 4; ++it) {
            const int r = it * 32 + rs;
            gload16(Bt + (size_t)(nt * 128 + r) * K + k0 + cs * 8,
                    (char*)Bl + (it * 256 + w * 64) * 16);
        }
        __syncthreads();
#pragma unroll
        for (int ks = 0; ks < 2; ++ks) {
            bh8 af[4], bv[4];
#pragma unroll
            for (int fm = 0; fm < 4; ++fm)
                af[fm] = *(const bh8*)&Al[(wr * 64 + fm * 16 + lrow) * 64 + ks * 32 + lkb];
#pragma unroll
            for (int fn = 0; fn < 4; ++fn)
                bv[fn] = *(const bh8*)&Bl[(wc * 64 + fn * 16 + lrow) * 64 + ks * 32 + lkb];
#pragma unroll
            for (int fm = 0; fm < 4; ++fm)
#pragma unroll
                for (int fn = 0; fn < 4; ++fn)
                    acc[fm][fn] = mfma16(af[fm], bv[fn], acc[fm][fn]);
        }
        __syncthreads();
    }

    const int r0 = mt * 128 + wr * 64 + (lane >> 4) * 4;
    const int c0 = nt * 128 + wc * 64 + lrow;
#pragma unroll
    for (int fn = 0; fn < 4; ++fn) {
        const int col = c0 + fn * 16;
        const float bvl = (EPI == 1 || EPI == 2) ? bias[col] : 0.0f;
#pragma unroll
        for (int fm = 0; fm < 4; ++fm) {
#pragma unroll
            for (int i = 0; i < 4; ++i) {
                const int rr = r0 + fm * 16 + i;
                const float v = acc[fm][fn][i];
                if (EPI == 0) {
                    outb[(size_t)rr * N + col] = f2bf(v);
                } else if (EPI == 1) {
                    const size_t idx = (size_t)rr * N + col;
                    outf[idx] = resid[idx] + v + bvl;
                } else if (EPI == 2) {
                    outb[(size_t)rr * N + col] = f2bf(fmaxf(v + bvl, 0.0f));
                } else {
                    outb[(size_t)(col >> 10) * 8388608 + (size_t)rr * 1024 + (col & 1023)]
                        = f2bf(v);
                }
            }
        }
    }
}

// ---------- causal flash attention, bf16 MFMA ----------
// Q,K,O: bf16 [b*1024 + t][h*64 + d] (row stride 1024)
// Vt: bf16 [bh][64 d][1024 t]
// grid = (8, 128); block bx does q-tiles {bx, 15-bx} (uniform 17 k-tiles)
__global__ __launch_bounds__(256, 3) void attn_kernel(
    const u16* __restrict__ Q, const u16* __restrict__ K,
    const u16* __restrict__ Vt, u16* __restrict__ O)
{
    __shared__ u16 Kl[2][64 * 64];
    __shared__ u16 Vl[2][64 * 64];
    __shared__ u16 Pl[4][16 * 72];       // padded stride 72: conflict-free r/w

    const int tid  = threadIdx.x;
    const int lane = tid & 63;
    const int w    = tid >> 6;
    const int bh   = blockIdx.y;
    const size_t base  = (size_t)(bh >> 4) * (1024 * 1024) + (bh & 15) * 64;
    const size_t vbase = (size_t)bh * 65536;
    const int lrow = lane & 15;
    const int lg   = lane >> 4;
    const int lkb  = lg * 8;
    const int rs   = tid >> 3, cs = tid & 7;

    const u16* Kp = K + base;
    const u16* Vp = Vt + vbase;

#pragma unroll 1
    for (int p = 0; p < 2; ++p) {
        const int qt = p ? (15 - blockIdx.x) : blockIdx.x;
        const int q0 = qt * 64;

        // Q fragments straight from global (once per q-tile)
        const bh8 aq0 = *(const bh8*)(Q + base + (size_t)(q0 + w * 16 + lrow) * 1024 + lkb);
        const bh8 aq1 = *(const bh8*)(Q + base + (size_t)(q0 + w * 16 + lrow) * 1024 + 32 + lkb);

        f4 o[4] = {};
        float mi[4], li[4];
#pragma unroll
        for (int i = 0; i < 4; ++i) { mi[i] = -__builtin_inff(); li[i] = 0.0f; }

        // prologue: stage tile 0 into buf 0 (source-swizzled so LDS stays linear)
#pragma unroll
        for (int it = 0; it < 2; ++it) {
            const int r = it * 32 + rs;
            gload16(Kp + (size_t)r * 1024 + ((cs ^ (r & 7)) * 8),
                    (char*)Kl[0] + it * 4096 + tid * 16);
            gload16(Vp + (size_t)r * 1024 + ((cs ^ (r & 7)) * 8),
                    (char*)Vl[0] + it * 4096 + tid * 16);
        }
        __syncthreads();

        for (int t = 0; t <= qt; ++t) {
            const int cur = t & 1;
            if (t < qt) {           // prefetch next tile into other buffer
                const int s1 = (t + 1) * 64;
#pragma unroll
                for (int it = 0; it < 2; ++it) {
                    const int r = it * 32 + rs;
                    gload16(Kp + (size_t)(s1 + r) * 1024 + ((cs ^ (r & 7)) * 8),
                            (char*)Kl[cur ^ 1] + it * 4096 + tid * 16);
                    gload16(Vp + (size_t)r * 1024 + s1 + ((cs ^ (r & 7)) * 8),
                            (char*)Vl[cur ^ 1] + it * 4096 + tid * 16);
                }
            }

            // QK^T (swizzled K reads)
            f4 sc[4] = {};
#pragma unroll
            for (int ks = 0; ks < 2; ++ks) {
                const bh8 a = ks ? aq1 : aq0;
#pragma unroll
                for (int fn = 0; fn < 4; ++fn) {
                    const int R = fn * 16 + lrow;
                    const bh8 bk = *(const bh8*)&Kl[cur][R * 64 + ((((ks << 2) + lg) ^ (R & 7)) * 8)];
                    sc[fn] = mfma16(a, bk, sc[fn]);
                }
            }
            // scale + causal mask (diagonal tile only); wave w owns rows w*16+r
            const bool diag = (t == qt);
#pragma unroll
            for (int fn = 0; fn < 4; ++fn)
#pragma unroll
                for (int i = 0; i < 4; ++i) {
                    float v = sc[fn][i] * 0.125f;
                    if (diag) {
                        const int r = lg * 4 + i;
                        const int c = fn * 16 + lrow;
                        if (c > w * 16 + r) v = -__builtin_inff();
                    }
                    sc[fn][i] = v;
                }
            // online softmax per q-row (16-lane group reduction)
#pragma unroll
            for (int i = 0; i < 4; ++i) {
                float pm = fmaxf(fmaxf(sc[0][i], sc[1][i]), fmaxf(sc[2][i], sc[3][i]));
#pragma unroll
                for (int m = 1; m < 16; m <<= 1) pm = fmaxf(pm, __shfl_xor(pm, m));
                const float mn   = fmaxf(mi[i], pm);
                const float corr = __expf(mi[i] - mn);
                float rsum = 0.0f;
#pragma unroll
                for (int fn = 0; fn < 4; ++fn) {
                    const float pv = __expf(sc[fn][i] - mn);
                    sc[fn][i] = pv;
                    rsum += pv;
                }
#pragma unroll
                for (int m = 1; m < 16; m <<= 1) rsum += __shfl_xor(rsum, m);
                li[i] = li[i] * corr + rsum;
                mi[i] = mn;
#pragma unroll
                for (int fn = 0; fn < 4; ++fn) o[fn][i] *= corr;
            }
            // P strip (wave-private, padded stride 72)
#pragma unroll
            for (int fn = 0; fn < 4; ++fn)
#pragma unroll
                for (int i = 0; i < 4; ++i)
                    Pl[w][(lg * 4 + i) * 72 + fn * 16 + lrow] = f2bf(sc[fn][i]);
            // PV (swizzled V reads; Vl rows are d, cols are s)
#pragma unroll
            for (int ss = 0; ss < 2; ++ss) {
                const bh8 ap = *(const bh8*)&Pl[w][lrow * 72 + ss * 32 + lkb];
#pragma unroll
                for (int fn = 0; fn < 4; ++fn) {
                    const int R = fn * 16 + lrow;
                    const bh8 bv = *(const bh8*)&Vl[cur][R * 64 + ((((ss << 2) + lg) ^ (R & 7)) * 8)];
                    o[fn] = mfma16(ap, bv, o[fn]);
                }
            }
            __syncthreads();
        }

        // write O (bf16)
#pragma unroll
        for (int fn = 0; fn < 4; ++fn)
#pragma unroll
            for (int i = 0; i < 4; ++i) {
                const int r = q0 + w * 16 + lg * 4 + i;
                const int c = fn * 16 + lrow;
                O[base + (size_t)r * 1024 + c] = f2bf(o[fn][i] / li[i]);
            }
    }
}

// ---------- launch ----------
extern "C" void kernel_launch(void* const* d_in, const int* in_sizes, int n_in,
                              void* d_out, int out_size, void* d_ws, size_t ws_size,
                              hipStream_t stream) {
    const float* x    = (const float*)d_in[0];
    const float* Wq   = (const float*)d_in[1];
    const float* Wk   = (const float*)d_in[2];
    const float* Wv   = (const float*)d_in[3];
    const float* Wp   = (const float*)d_in[4];
    const float* bp   = (const float*)d_in[5];
    const float* ln1g = (const float*)d_in[6];
    const float* ln1b = (const float*)d_in[7];
    const float* ln2g = (const float*)d_in[8];
    const float* ln2b = (const float*)d_in[9];
    const float* W1   = (const float*)d_in[10];
    const float* b1   = (const float*)d_in[11];
    const float* W2   = (const float*)d_in[12];
    const float* b2   = (const float*)d_in[13];
    float* out = (float*)d_out;

    // ws layout (u16 elements). Peak usage: 104 MB (same as before).
    u16* ws   = (u16*)d_ws;
    u16* wqkt = ws;                       // [3072][1024] fused qkv weights
    u16* wpt  = wqkt + (3u << 20);
    u16* w1t  = wpt  + (1u << 20);        // [4096][1024]
    u16* w2t  = w1t  + (4u << 20);        // [1024][4096]
    u16* qb   = w2t  + (4u << 20);        // [8192][1024]
    u16* kb   = qb   + (8u << 20);
    u16* vb   = kb   + (8u << 20);        // V row-major; later attn-out
    u16* xnb  = vb   + (8u << 20);        // xn; later V-transposed [bh][64][1024]
    u16* vtb  = xnb;
    u16* aob  = vb;
    u16* xn2b = qb;                       // q dead after attention
    u16* h1b  = kb;                       // [8192][4096] overlays kb..xnb+16MB

    dim3 blk(256);
    wconv_kernel<<<dim3(32, 32),  blk, 0, stream>>>(Wq, wqkt,              1024, 1024);
    wconv_kernel<<<dim3(32, 32),  blk, 0, stream>>>(Wk, wqkt + (1u << 20), 1024, 1024);
    wconv_kernel<<<dim3(32, 32),  blk, 0, stream>>>(Wv, wqkt + (2u << 20), 1024, 1024);
    wconv_kernel<<<dim3(32, 32),  blk, 0, stream>>>(Wp, wpt, 1024, 1024);
    wconv_kernel<<<dim3(128, 32), blk, 0, stream>>>(W1, w1t, 1024, 4096);
    wconv_kernel<<<dim3(32, 128), blk, 0, stream>>>(W2, w2t, 4096, 1024);

    ln_kernel<<<8192, blk, 0, stream>>>(x, ln1g, ln1b, xnb);

    // fused QKV: one GEMM, split epilogue into contiguous qb/kb/vb
    gemm_kernel<3><<<dim3(24, 64), blk, 0, stream>>>(xnb, wqkt, 8192, 3072, 1024,
                                                     nullptr, nullptr, nullptr, qb);

    vtrans_kernel<<<dim3(16, 128), blk, 0, stream>>>(vb, vtb);

    attn_kernel<<<dim3(8, 128), blk, 0, stream>>>(qb, kb, vtb, aob);

    gemm_kernel<1><<<dim3(8, 64), blk, 0, stream>>>(aob, wpt, 8192, 1024, 1024,
                                                    bp, x, out, nullptr);

    ln_kernel<<<8192, blk, 0, stream>>>(out, ln2g, ln2b, xn2b);

    gemm_kernel<2><<<dim3(32, 64), blk, 0, stream>>>(xn2b, w1t, 8192, 4096, 1024,
                                                     b1, nullptr, nullptr, h1b);
    gemm_kernel<1><<<dim3(8, 64), blk, 0, stream>>>(h1b, w2t, 8192, 1024, 4096,
                                                    b2, out, out, nullptr);
}

// Round 5
// 385.755 us; speedup vs baseline: 1.3992x; 1.0341x over previous
//
#include <hip/hip_runtime.h>
#include <cstdint>
#include <cstddef>

using u16 = unsigned short;
typedef __attribute__((ext_vector_type(8))) short bh8;   // 8 x bf16 (4 VGPRs)
typedef __attribute__((ext_vector_type(4))) float f4;    // MFMA accumulator

// ---------- helpers ----------
__device__ __forceinline__ u16 f2bf(float f) {
    union { float f; uint32_t u; } c; c.f = f;
    uint32_t u = c.u;
    u += 0x7FFFu + ((u >> 16) & 1u);   // RNE
    return (u16)(u >> 16);
}

__device__ __forceinline__ void gload16(const void* g, void* l) {
    // async global->LDS, 16B per lane; LDS dest = wave-uniform base + lane*16
    __builtin_amdgcn_global_load_lds(
        (__attribute__((address_space(1))) void*)g,
        (__attribute__((address_space(3))) void*)l,
        16, 0, 0);
}

__device__ __forceinline__ f4 mfma16(bh8 a, bh8 b, f4 c) {
    return __builtin_amdgcn_mfma_f32_16x16x32_bf16(a, b, c, 0, 0, 0);
}

// ---------- weight transpose + f32 -> bf16 ----------
__global__ __launch_bounds__(256) void wconv_kernel(
    const float* __restrict__ W, u16* __restrict__ Wt, int K, int N)
{
    __shared__ float t[32][33];
    const int tx = threadIdx.x & 31, ty = threadIdx.x >> 5;
    const int n0 = blockIdx.x * 32, k0 = blockIdx.y * 32;
#pragma unroll
    for (int j = 0; j < 4; ++j)
        t[ty + 8 * j][tx] = W[(size_t)(k0 + ty + 8 * j) * N + n0 + tx];
    __syncthreads();
#pragma unroll
    for (int j = 0; j < 4; ++j)
        Wt[(size_t)(n0 + ty + 8 * j) * K + k0 + tx] = f2bf(t[tx][ty + 8 * j]);
}

// ---------- layernorm: f32 [rows][1024] -> bf16 ----------
__global__ __launch_bounds__(256) void ln_kernel(
    const float* __restrict__ x, const float* __restrict__ g,
    const float* __restrict__ b, u16* __restrict__ out)
{
    const int row = blockIdx.x;
    const int tid = threadIdx.x;
    const float4 v = ((const float4*)(x + (size_t)row * 1024))[tid];
    float s  = v.x + v.y + v.z + v.w;
    float sq = v.x * v.x + v.y * v.y + v.z * v.z + v.w * v.w;
#pragma unroll
    for (int m = 1; m < 64; m <<= 1) {
        s  += __shfl_xor(s, m);
        sq += __shfl_xor(sq, m);
    }
    __shared__ float red[8];
    const int w = tid >> 6;
    if ((tid & 63) == 0) { red[w * 2] = s; red[w * 2 + 1] = sq; }
    __syncthreads();
    s  = red[0] + red[2] + red[4] + red[6];
    sq = red[1] + red[3] + red[5] + red[7];
    const float mu   = s * (1.0f / 1024.0f);
    const float var  = sq * (1.0f / 1024.0f) - mu * mu;
    const float rstd = rsqrtf(var + 1e-5f);
    const float4 gv = ((const float4*)g)[tid];
    const float4 bv = ((const float4*)b)[tid];
    ushort4 o;
    o.x = f2bf((v.x - mu) * rstd * gv.x + bv.x);
    o.y = f2bf((v.y - mu) * rstd * gv.y + bv.y);
    o.z = f2bf((v.z - mu) * rstd * gv.z + bv.z);
    o.w = f2bf((v.w - mu) * rstd * gv.w + bv.w);
    ((ushort4*)(out + (size_t)row * 1024))[tid] = o;
}

// ---------- V transpose: vb [8192][1024] -> vtb [bh][64 d][1024 t] ----------
__global__ __launch_bounds__(256) void vtrans_kernel(
    const u16* __restrict__ vb, u16* __restrict__ vtb)
{
    __shared__ u16 t[64][66];
    const int bh = blockIdx.y;
    const int t0 = blockIdx.x * 64;
    const int b = bh >> 4, h = bh & 15;
    const u16* src = vb + (size_t)b * 1024 * 1024 + h * 64;
    const int rs = threadIdx.x >> 3, cs = threadIdx.x & 7;
#pragma unroll
    for (int it = 0; it < 2; ++it) {
        const int r = it * 32 + rs;
        *(uint4*)&t[r][cs * 8] = *(const uint4*)(src + (size_t)(t0 + r) * 1024 + cs * 8);
    }
    __syncthreads();
    u16* dst = vtb + (size_t)bh * 65536 + t0;
#pragma unroll
    for (int it = 0; it < 2; ++it) {
        const int d = it * 32 + rs;
        u16 tmp[8];
#pragma unroll
        for (int j = 0; j < 8; ++j) tmp[j] = t[cs * 8 + j][d];
        *(uint4*)(dst + (size_t)d * 1024 + cs * 8) = *(const uint4*)tmp;
    }
}

// ---------- old 128x128 2-phase GEMM (kept for proj as in-bench baseline) ----------
// EPI 1: outf = resid + acc + bias
template <int EPI>
__global__ __launch_bounds__(256, 2) void gemm_kernel(
    const u16* __restrict__ A, const u16* __restrict__ Bt,
    int M, int N, int K,
    const float* __restrict__ bias, const float* __restrict__ resid,
    float* __restrict__ outf, u16* __restrict__ outb)
{
    __shared__ u16 Al[128 * 64];
    __shared__ u16 Bl[128 * 64];
    const int tid  = threadIdx.x;
    const int lane = tid & 63;
    const int w    = tid >> 6;
    const int wr   = w >> 1, wc = w & 1;
    const int mt   = blockIdx.y, nt = blockIdx.x;
    const int lrow = lane & 15;
    const int lkb  = (lane >> 4) * 8;
    const int rs   = tid >> 3;
    const int cs   = tid & 7;

    f4 acc[4][4] = {};

    for (int k0 = 0; k0 < K; k0 += 64) {
#pragma unroll
        for (int it = 0; it < 4; ++it) {
            const int r = it * 32 + rs;
            gload16(A + (size_t)(mt * 128 + r) * K + k0 + cs * 8,
                    (char*)Al + (it * 256 + w * 64) * 16);
        }
#pragma unroll
        for (int it = 0; it < 4; ++it) {
            const int r = it * 32 + rs;
            gload16(Bt + (size_t)(nt * 128 + r) * K + k0 + cs * 8,
                    (char*)Bl + (it * 256 + w * 64) * 16);
        }
        __syncthreads();
#pragma unroll
        for (int ks = 0; ks < 2; ++ks) {
            bh8 af[4], bv[4];
#pragma unroll
            for (int fm = 0; fm < 4; ++fm)
                af[fm] = *(const bh8*)&Al[(wr * 64 + fm * 16 + lrow) * 64 + ks * 32 + lkb];
#pragma unroll
            for (int fn = 0; fn < 4; ++fn)
                bv[fn] = *(const bh8*)&Bl[(wc * 64 + fn * 16 + lrow) * 64 + ks * 32 + lkb];
#pragma unroll
            for (int fm = 0; fm < 4; ++fm)
#pragma unroll
                for (int fn = 0; fn < 4; ++fn)
                    acc[fm][fn] = mfma16(af[fm], bv[fn], acc[fm][fn]);
        }
        __syncthreads();
    }

    const int r0 = mt * 128 + wr * 64 + (lane >> 4) * 4;
    const int c0 = nt * 128 + wc * 64 + lrow;
#pragma unroll
    for (int fn = 0; fn < 4; ++fn) {
        const int col = c0 + fn * 16;
        const float bvl = bias[col];
#pragma unroll
        for (int fm = 0; fm < 4; ++fm) {
#pragma unroll
            for (int i = 0; i < 4; ++i) {
                const size_t idx = (size_t)(r0 + fm * 16 + i) * N + col;
                outf[idx] = resid[idx] + acc[fm][fn][i] + bvl;
            }
        }
    }
}

// ---------- 256-wide 8-wave 4-phase counted-vmcnt GEMM (m201-style phases) ----------
// C[M][N] = A[M][K] * Bt[N][K]^T. BM=256, BN=64*NF, BK=64, 512 threads.
// Each phase: {issue ds_reads + 1 half-tile stage; barrier; lgkmcnt(0);
// sched_barrier; setprio(1); 16 MFMA; setprio(0); [ph4: vmcnt(2)]; barrier}.
// The per-phase lgkmcnt(0) drain is the correctness invariant: no ds_read
// crosses a phase-end barrier, so ph4's same-slot stage (A-h0(t+2)->s)
// cannot race ph1/ph3 reads of Al[s]. vmcnt(2)+barrier once per K-tile
// gates tile t+1's loads (only A-h0(t+2) may stay in flight).
// EPI 1: outf = resid + acc + bias;  2: outb = bf16(relu(acc+bias));
// EPI 3: qkv split (col>>10 selects segment of 8M u16)
template <int NF, int EPI>
__global__ __launch_bounds__(512) void gemm8_kernel(
    const u16* __restrict__ A, const u16* __restrict__ Bt,
    int M, int N, int K,
    const float* __restrict__ bias, const float* __restrict__ resid,
    float* __restrict__ outf, u16* __restrict__ outb)
{
    constexpr int BN = NF * 64;
    __shared__ u16 Al[2][256 * 64];
    __shared__ u16 Bl[2][BN * 64];

    const int tid  = threadIdx.x;
    const int lane = tid & 63;
    const int w    = tid >> 6;
    const int wr   = w >> 2;        // 0..1 (m)
    const int wc   = w & 3;         // 0..3 (n)
    const int lrow = lane & 15;
    const int lg   = lane >> 4;

    // bijective XCD swizzle (all launches have nwg % 8 == 0)
    const int gx  = gridDim.x;
    const int nwg = gx * gridDim.y;
    const int lin = blockIdx.y * gx + blockIdx.x;
    const int swz = (lin & 7) * (nwg >> 3) + (lin >> 3);
    const int nt  = swz % gx, mt = swz / gx;

    const int NT = K >> 6;

    auto stageA = [&](int slot, int h, int kt) {
#pragma unroll
        for (int it = 0; it < 2; ++it) {
            const int r = h * 128 + it * 64 + (tid >> 3);
            gload16(A + (size_t)(mt * 256 + r) * K + kt * 64 + (((tid & 7) ^ (r & 7)) << 3),
                    (char*)Al[slot] + (h * 128 + it * 64) * 128 + tid * 16);
        }
    };
    auto stageB = [&](int slot, int h, int kt) {
#pragma unroll
        for (int it = 0; it < NF / 2; ++it) {
            const int r = h * (BN / 2) + it * 64 + (tid >> 3);
            gload16(Bt + (size_t)(nt * BN + r) * K + kt * 64 + (((tid & 7) ^ (r & 7)) << 3),
                    (char*)Bl[slot] + (h * (BN / 2) + it * 64) * 128 + tid * 16);
        }
    };

    f4 acc[8][NF] = {};
    bh8 af[8];
    bh8 bf[NF];

    auto readFrags = [&](int slot, int ks) {
#pragma unroll
        for (int fm = 0; fm < 8; ++fm) {
            const int R = wr * 128 + fm * 16 + lrow;
            af[fm] = *(const bh8*)&Al[slot][R * 64 + ((((ks << 2) + lg) ^ (R & 7)) << 3)];
        }
#pragma unroll
        for (int fn = 0; fn < NF; ++fn) {
            const int R = wc * (NF * 16) + fn * 16 + lrow;
            bf[fn] = *(const bh8*)&Bl[slot][R * 64 + ((((ks << 2) + lg) ^ (R & 7)) << 3)];
        }
    };
    auto mfmaHalf = [&](int mh) {
#pragma unroll
        for (int fm = 0; fm < 4; ++fm)
#pragma unroll
            for (int fn = 0; fn < NF; ++fn)
                acc[mh * 4 + fm][fn] = mfma16(af[mh * 4 + fm], bf[fn], acc[mh * 4 + fm][fn]);
    };

    // prologue: tile0 (4 halves) + tile1 A-h0; wait all but last stage
    stageA(0, 0, 0); stageA(0, 1, 0); stageB(0, 0, 0); stageB(0, 1, 0);
    stageA(1, 0, 1);
    asm volatile("s_waitcnt vmcnt(2)" ::: "memory");
    __builtin_amdgcn_s_barrier();
    __builtin_amdgcn_sched_barrier(0);

    auto doTile = [&](int t, int s) {
        // ---- ph1: read ks0 frags(s); stage A-h1(t+1)->s^1
        readFrags(s, 0);
        if (t + 1 < NT) stageA(s ^ 1, 1, t + 1);
        __builtin_amdgcn_s_barrier();
        asm volatile("s_waitcnt lgkmcnt(0)" ::: "memory");
        __builtin_amdgcn_sched_barrier(0);
        __builtin_amdgcn_s_setprio(1);
        mfmaHalf(0);
        __builtin_amdgcn_s_setprio(0);
        __builtin_amdgcn_s_barrier();
        __builtin_amdgcn_sched_barrier(0);
        // ---- ph2: stage B-h0(t+1)->s^1
        if (t + 1 < NT) stageB(s ^ 1, 0, t + 1);
        __builtin_amdgcn_s_barrier();
        __builtin_amdgcn_sched_barrier(0);
        __builtin_amdgcn_s_setprio(1);
        mfmaHalf(1);
        __builtin_amdgcn_s_setprio(0);
        __builtin_amdgcn_s_barrier();
        __builtin_amdgcn_sched_barrier(0);
        // ---- ph3: read ks1 frags(s); stage B-h1(t+1)->s^1
        readFrags(s, 1);
        if (t + 1 < NT) stageB(s ^ 1, 1, t + 1);
        __builtin_amdgcn_s_barrier();
        asm volatile("s_waitcnt lgkmcnt(0)" ::: "memory");
        __builtin_amdgcn_sched_barrier(0);
        __builtin_amdgcn_s_setprio(1);
        mfmaHalf(0);
        __builtin_amdgcn_s_setprio(0);
        __builtin_amdgcn_s_barrier();
        __builtin_amdgcn_sched_barrier(0);
        // ---- ph4: stage A-h0(t+2)->s; vmcnt(2) gate; tile end
        if (t + 2 < NT) stageA(s, 0, t + 2);
        __builtin_amdgcn_s_barrier();
        __builtin_amdgcn_sched_barrier(0);
        __builtin_amdgcn_s_setprio(1);
        mfmaHalf(1);
        __builtin_amdgcn_s_setprio(0);
        asm volatile("s_waitcnt vmcnt(2)" ::: "memory");
        __builtin_amdgcn_s_barrier();
        __builtin_amdgcn_sched_barrier(0);
    };

    for (int t = 0; t < NT; t += 2) { doTile(t, 0); doTile(t + 1, 1); }

    // epilogue
    const int r0 = mt * 256 + wr * 128 + lg * 4;
    const int c0 = nt * BN + wc * (NF * 16) + lrow;
#pragma unroll
    for (int fn = 0; fn < NF; ++fn) {
        const int col = c0 + fn * 16;
        const float bvl = (EPI == 1 || EPI == 2) ? bias[col] : 0.0f;
#pragma unroll
        for (int fm = 0; fm < 8; ++fm) {
#pragma unroll
            for (int i = 0; i < 4; ++i) {
                const int rr = r0 + fm * 16 + i;
                const float v = acc[fm][fn][i];
                if (EPI == 1) {
                    const size_t idx = (size_t)rr * N + col;
                    outf[idx] = resid[idx] + v + bvl;
                } else if (EPI == 2) {
                    outb[(size_t)rr * N + col] = f2bf(fmaxf(v + bvl, 0.0f));
                } else {
                    outb[(size_t)(col >> 10) * 8388608 + (size_t)rr * 1024 + (col & 1023)]
                        = f2bf(v);
                }
            }
        }
    }
}

// ---------- causal flash attention, bf16 MFMA ----------
__global__ __launch_bounds__(256, 3) void attn_kernel(
    const u16* __restrict__ Q, const u16* __restrict__ K,
    const u16* __restrict__ Vt, u16* __restrict__ O)
{
    __shared__ u16 Kl[2][64 * 64];
    __shared__ u16 Vl[2][64 * 64];
    __shared__ u16 Pl[4][16 * 72];

    const int tid  = threadIdx.x;
    const int lane = tid & 63;
    const int w    = tid >> 6;
    const int bh   = blockIdx.y;
    const size_t base  = (size_t)(bh >> 4) * (1024 * 1024) + (bh & 15) * 64;
    const size_t vbase = (size_t)bh * 65536;
    const int lrow = lane & 15;
    const int lg   = lane >> 4;
    const int lkb  = lg * 8;
    const int rs   = tid >> 3, cs = tid & 7;

    const u16* Kp = K + base;
    const u16* Vp = Vt + vbase;

#pragma unroll 1
    for (int p = 0; p < 2; ++p) {
        const int qt = p ? (15 - blockIdx.x) : blockIdx.x;
        const int q0 = qt * 64;

        const bh8 aq0 = *(const bh8*)(Q + base + (size_t)(q0 + w * 16 + lrow) * 1024 + lkb);
        const bh8 aq1 = *(const bh8*)(Q + base + (size_t)(q0 + w * 16 + lrow) * 1024 + 32 + lkb);

        f4 o[4] = {};
        float mi[4], li[4];
#pragma unroll
        for (int i = 0; i < 4; ++i) { mi[i] = -__builtin_inff(); li[i] = 0.0f; }

#pragma unroll
        for (int it = 0; it < 2; ++it) {
            const int r = it * 32 + rs;
            gload16(Kp + (size_t)r * 1024 + ((cs ^ (r & 7)) * 8),
                    (char*)Kl[0] + it * 4096 + tid * 16);
            gload16(Vp + (size_t)r * 1024 + ((cs ^ (r & 7)) * 8),
                    (char*)Vl[0] + it * 4096 + tid * 16);
        }
        __syncthreads();

        for (int t = 0; t <= qt; ++t) {
            const int cur = t & 1;
            if (t < qt) {
                const int s1 = (t + 1) * 64;
#pragma unroll
                for (int it = 0; it < 2; ++it) {
                    const int r = it * 32 + rs;
                    gload16(Kp + (size_t)(s1 + r) * 1024 + ((cs ^ (r & 7)) * 8),
                            (char*)Kl[cur ^ 1] + it * 4096 + tid * 16);
                    gload16(Vp + (size_t)r * 1024 + s1 + ((cs ^ (r & 7)) * 8),
                            (char*)Vl[cur ^ 1] + it * 4096 + tid * 16);
                }
            }

            f4 sc[4] = {};
#pragma unroll
            for (int ks = 0; ks < 2; ++ks) {
                const bh8 a = ks ? aq1 : aq0;
#pragma unroll
                for (int fn = 0; fn < 4; ++fn) {
                    const int R = fn * 16 + lrow;
                    const bh8 bk = *(const bh8*)&Kl[cur][R * 64 + ((((ks << 2) + lg) ^ (R & 7)) * 8)];
                    sc[fn] = mfma16(a, bk, sc[fn]);
                }
            }
            const bool diag = (t == qt);
#pragma unroll
            for (int fn = 0; fn < 4; ++fn)
#pragma unroll
                for (int i = 0; i < 4; ++i) {
                    float v = sc[fn][i] * 0.125f;
                    if (diag) {
                        const int r = lg * 4 + i;
                        const int c = fn * 16 + lrow;
                        if (c > w * 16 + r) v = -__builtin_inff();
                    }
                    sc[fn][i] = v;
                }
#pragma unroll
            for (int i = 0; i < 4; ++i) {
                float pm = fmaxf(fmaxf(sc[0][i], sc[1][i]), fmaxf(sc[2][i], sc[3][i]));
#pragma unroll
                for (int m = 1; m < 16; m <<= 1) pm = fmaxf(pm, __shfl_xor(pm, m));
                const float mn   = fmaxf(mi[i], pm);
                const float corr = __expf(mi[i] - mn);
                float rsum = 0.0f;
#pragma unroll
                for (int fn = 0; fn < 4; ++fn) {
                    const float pv = __expf(sc[fn][i] - mn);
                    sc[fn][i] = pv;
                    rsum += pv;
                }
#pragma unroll
                for (int m = 1; m < 16; m <<= 1) rsum += __shfl_xor(rsum, m);
                li[i] = li[i] * corr + rsum;
                mi[i] = mn;
#pragma unroll
                for (int fn = 0; fn < 4; ++fn) o[fn][i] *= corr;
            }
#pragma unroll
            for (int fn = 0; fn < 4; ++fn)
#pragma unroll
                for (int i = 0; i < 4; ++i)
                    Pl[w][(lg * 4 + i) * 72 + fn * 16 + lrow] = f2bf(sc[fn][i]);
#pragma unroll
            for (int ss = 0; ss < 2; ++ss) {
                const bh8 ap = *(const bh8*)&Pl[w][lrow * 72 + ss * 32 + lkb];
#pragma unroll
                for (int fn = 0; fn < 4; ++fn) {
                    const int R = fn * 16 + lrow;
                    const bh8 bv = *(const bh8*)&Vl[cur][R * 64 + ((((ss << 2) + lg) ^ (R & 7)) * 8)];
                    o[fn] = mfma16(ap, bv, o[fn]);
                }
            }
            __syncthreads();
        }

#pragma unroll
        for (int fn = 0; fn < 4; ++fn)
#pragma unroll
            for (int i = 0; i < 4; ++i) {
                const int r = q0 + w * 16 + lg * 4 + i;
                const int c = fn * 16 + lrow;
                O[base + (size_t)r * 1024 + c] = f2bf(o[fn][i] / li[i]);
            }
    }
}

// ---------- launch ----------
extern "C" void kernel_launch(void* const* d_in, const int* in_sizes, int n_in,
                              void* d_out, int out_size, void* d_ws, size_t ws_size,
                              hipStream_t stream) {
    const float* x    = (const float*)d_in[0];
    const float* Wq   = (const float*)d_in[1];
    const float* Wk   = (const float*)d_in[2];
    const float* Wv   = (const float*)d_in[3];
    const float* Wp   = (const float*)d_in[4];
    const float* bp   = (const float*)d_in[5];
    const float* ln1g = (const float*)d_in[6];
    const float* ln1b = (const float*)d_in[7];
    const float* ln2g = (const float*)d_in[8];
    const float* ln2b = (const float*)d_in[9];
    const float* W1   = (const float*)d_in[10];
    const float* b1   = (const float*)d_in[11];
    const float* W2   = (const float*)d_in[12];
    const float* b2   = (const float*)d_in[13];
    float* out = (float*)d_out;

    u16* ws   = (u16*)d_ws;
    u16* wqkt = ws;                       // [3072][1024] fused qkv weights
    u16* wpt  = wqkt + (3u << 20);
    u16* w1t  = wpt  + (1u << 20);        // [4096][1024]
    u16* w2t  = w1t  + (4u << 20);        // [1024][4096]
    u16* qb   = w2t  + (4u << 20);        // [8192][1024]
    u16* kb   = qb   + (8u << 20);
    u16* vb   = kb   + (8u << 20);        // V row-major; later attn-out
    u16* xnb  = vb   + (8u << 20);        // xn; later V-transposed [bh][64][1024]
    u16* vtb  = xnb;
    u16* aob  = vb;
    u16* xn2b = qb;
    u16* h1b  = kb;                       // [8192][4096]

    dim3 blk(256);
    wconv_kernel<<<dim3(32, 32),  blk, 0, stream>>>(Wq, wqkt,              1024, 1024);
    wconv_kernel<<<dim3(32, 32),  blk, 0, stream>>>(Wk, wqkt + (1u << 20), 1024, 1024);
    wconv_kernel<<<dim3(32, 32),  blk, 0, stream>>>(Wv, wqkt + (2u << 20), 1024, 1024);
    wconv_kernel<<<dim3(32, 32),  blk, 0, stream>>>(Wp, wpt, 1024, 1024);
    wconv_kernel<<<dim3(128, 32), blk, 0, stream>>>(W1, w1t, 1024, 4096);
    wconv_kernel<<<dim3(32, 128), blk, 0, stream>>>(W2, w2t, 4096, 1024);

    ln_kernel<<<8192, blk, 0, stream>>>(x, ln1g, ln1b, xnb);

    // fused QKV: 256-tile 4-phase kernel, split epilogue
    gemm8_kernel<4, 3><<<dim3(12, 32), 512, 0, stream>>>(xnb, wqkt, 8192, 3072, 1024,
                                                         nullptr, nullptr, nullptr, qb);

    vtrans_kernel<<<dim3(16, 128), blk, 0, stream>>>(vb, vtb);

    attn_kernel<<<dim3(8, 128), blk, 0, stream>>>(qb, kb, vtb, aob);

    // proj: old 128-tile kernel (in-bench baseline control)
    gemm_kernel<1><<<dim3(8, 64), blk, 0, stream>>>(aob, wpt, 8192, 1024, 1024,
                                                    bp, x, out, nullptr);

    ln_kernel<<<8192, blk, 0, stream>>>(out, ln2g, ln2b, xn2b);

    gemm8_kernel<4, 2><<<dim3(16, 32), 512, 0, stream>>>(xn2b, w1t, 8192, 4096, 1024,
                                                         b1, nullptr, nullptr, h1b);
    gemm8_kernel<2, 1><<<dim3(8, 32), 512, 0, stream>>>(h1b, w2t, 8192, 1024, 4096,
                                                        b2, out, out, nullptr);
}